// Round 1
// baseline (21705.377 us; speedup 1.0000x reference)
//
#include <hip/hip_runtime.h>
#include <hip/hip_bf16.h>

typedef __bf16 bf16x8 __attribute__((ext_vector_type(8)));
typedef float f32x4 __attribute__((ext_vector_type(4)));
typedef unsigned int u32x4 __attribute__((ext_vector_type(4)));

#define BB   128
#define SS   512
#define DD   128
#define HH   1024
#define OO   64
#define IIN  257

// 8 batch groups (16 rows) x 64 blocks; block owns 16 h-cols (64 gate cols).
// 4 waves = 4 K-quarters, W_hh B-frags persistent in VGPRs. 2 blocks/CU from
// different groups hide each other's sync-chain latency.
#define NGROUP 8
#define GBLK   64
#define MG     16
#define KK_H   32     // 1024/32 ksteps
#define KK_X   9      // 288/32

#define XTP_TP    (KK_X*512)      // 4608 bf16 per (t,p)
#define HBUF_SLAB (KK_H*512)      // 16384 bf16 = 32 KB per (p,buf)
#define WIH_BLK   (4*KK_X*512)    // 18432 bf16 per q

// ws layout (bytes): flags 8K | hbuf 512K | hlast 512K | xtp 36M | wihp 2.25M
#define WS_HBUF  8192
#define WS_HLAST 532480
#define WS_XTP   1056768
#define WS_WIHP  38805504

// ---- device-scope (sc1) ops: bypass L1/L2, coherent at MALL.
__device__ __forceinline__ u32x4 ldg_dev16(const void* p) {
  u32x4 r;
  asm volatile("global_load_dwordx4 %0, %1, off sc1" : "=v"(r) : "v"(p));
  return r;
}
__device__ __forceinline__ void stg_dev4(void* p, unsigned int v) {
  asm volatile("global_store_dword %0, %1, off sc1" :: "v"(p), "v"(v));
}
__device__ __forceinline__ bf16x8 asbf(u32x4 v) {
  union { u32x4 u; bf16x8 h; } c; c.u = v; return c.h;
}

#define CLAIMW4(CNTSTR, A, O)                                        \
  asm volatile("s_waitcnt vmcnt(" CNTSTR ")"                         \
    : "+v"((A)[(O)]), "+v"((A)[(O)+1]), "+v"((A)[(O)+2]), "+v"((A)[(O)+3]))

// xtp A-frags (16x16x32 A: m=lane&15, k=kk*32+(lane>>4)*8+j):
// idx = ((t*8+p)*9 + kk)*512 + l*8 + j
__global__ void prepack_kernel(const float* __restrict__ x, const float* __restrict__ mask,
                               const float* __restrict__ ti, __bf16* __restrict__ xtp) {
  int idx = blockIdx.x * 256 + threadIdx.x;        // 18,874,368
  int j = idx & 7, l = (idx >> 3) & 63;
  int rest = idx >> 9;
  int kk = rest % 9;
  int rest2 = rest / 9;
  int p = rest2 & 7;
  int t = rest2 >> 3;
  int b = p * MG + (l & 15);
  int k = kk * 32 + ((l >> 4) << 3) + j;
  float v;
  if (k < 128)       v = x[(b * SS + t) * DD + k];
  else if (k < 256)  v = mask[(b * SS + t) * DD + (k - 128)];
  else if (k == 256) v = ti[b * SS + t];
  else               v = 0.f;
  xtp[idx] = (__bf16)v;
}

// W_ih B-frags per col-slice q: [q][nt][kk][lane][8], nt = gate
__global__ void wih_prepack(const float* __restrict__ W_ih, __bf16* __restrict__ wihp) {
  int idx = blockIdx.x * 256 + threadIdx.x;        // 1,179,648
  int j = idx & 7, l = (idx >> 3) & 63;
  int rest = idx >> 9;
  int kk = rest % 9;
  int rest2 = rest / 9;
  int nt = rest2 & 3, q = rest2 >> 2;
  int col = nt * HH + q * 16 + (l & 15);
  int k = kk * 32 + ((l >> 4) << 3) + j;
  wihp[idx] = (k < IIN) ? (__bf16)W_ih[col * IIN + k] : (__bf16)0.f;
}

__device__ __forceinline__ float sigmoid_f(float v) { return 1.f / (1.f + __expf(-v)); }
__device__ __forceinline__ float tanh_f(float v)    { return 1.f - 2.f / (__expf(2.f * v) + 1.f); }

__launch_bounds__(256, 2)
__global__ void lstm_scan(const float* __restrict__ W_hh,
                          const float* __restrict__ b_ih, const float* __restrict__ b_hh,
                          const __bf16* __restrict__ xtp, const __bf16* __restrict__ wihp,
                          __bf16* __restrict__ hbuf,
                          float* __restrict__ hlast, unsigned int* __restrict__ flags) {
  // conflict-free reduce buffer: slot(w,g,r,qh,n16) =
  //   (((w*4+g)*4+r)*4+qh)*32 + n16*2 + (qh&1)   -> bank = 2*n16+(qh&1), 2-way
  __shared__ float red_lds[8192];   // 32 KB

  const int tid = threadIdx.x;
  const int bid = blockIdx.x;
  const int p = bid >> 6;                      // batch group [0,8)
  const int q = bid & 63;                      // col slice within group
  const int j0 = q * 16;                       // owned h-cols [j0, j0+16)

  const int w = tid >> 6, l = tid & 63;        // wave = K-quarter
  const int n16 = l & 15, qh = l >> 4;
  unsigned int* gflags = flags + p * 256;      // 64 blocks x 4 wave-flags

  // ---- W_hh B-fragments persistent in VGPRs: [nt][i], kk = w*8+i ----
  bf16x8 breg[4][8];
  #pragma unroll
  for (int ntI = 0; ntI < 4; ++ntI) {
    const float* wrow = W_hh + (size_t)(ntI * HH + j0 + n16) * HH;
    #pragma unroll
    for (int i = 0; i < 8; ++i) {
      const float* src = wrow + (w * 8 + i) * 32 + qh * 8;
      bf16x8 bv;
      #pragma unroll
      for (int jj = 0; jj < 8; ++jj) bv[jj] = (__bf16)src[jj];
      breg[ntI][i] = bv;
    }
  }

  // gate-phase cell ownership: this thread owns (row = qh*4 + w, col = j0+n16)
  const int grow = qh * 4 + w;
  float bias_r[4];
  #pragma unroll
  for (int g = 0; g < 4; ++g)
    bias_r[g] = b_ih[g * HH + j0 + n16] + b_hh[g * HH + j0 + n16];
  float creg = 0.f;

  // x-part K split over waves: kk in [xs, xe)
  const int xs = (w == 0) ? 0 : (2 * w + 1);
  const int xe = xs + ((w == 0) ? 3 : 2);

  for (int t = 0; t < SS; ++t) {
    const int rb = t & 1, wb = rb ^ 1;
    f32x4 acc[4];
    #pragma unroll
    for (int ntI = 0; ntI < 4; ++ntI) acc[ntI] = (f32x4){0.f, 0.f, 0.f, 0.f};

    // x-part (this wave's K-slice), pre-poll; A from xtp, B from wihp (cached)
    for (int kk = xs; kk < xe; ++kk) {
      const __bf16* xb = xtp + ((size_t)(t * 8 + p) * KK_X + kk) * 512 + l * 8;
      bf16x8 a = *(const bf16x8*)xb;
      #pragma unroll
      for (int ntI = 0; ntI < 4; ++ntI) {
        bf16x8 b = *(const bf16x8*)(wihp + ((size_t)(q * 4 + ntI) * KK_X + kk) * 512 + l * 8);
        acc[ntI] = __builtin_amdgcn_mfma_f32_16x16x32_bf16(a, b, acc[ntI], 0, 0, 0);
      }
    }

    // ---- per-wave poll + h-part. Wave w consumes h-cols [256w, 256w+256) ==
    // blocks q' in [16w, 16w+16) == flags gflags[64w + lane] (1 dword/lane).
    // Union of the block's 4 wave-polls covers all 256 flags before the
    // deposit barrier, so the slab WAR-safety argument is unchanged.
    // t==0: h0 == 0 -> skip h-part entirely; hbuf is never read before being
    // written under flag protection (memset of hbuf no longer load-bearing).
    if (t > 0) {
      {
        const unsigned int tgt = (unsigned int)t;
        const unsigned int* fp = gflags + (w << 6) + l;
        for (;;) {
          unsigned int f;
          asm volatile("global_load_dword %0, %1, off sc1\n\t"
                       "s_waitcnt vmcnt(0)"
                       : "=v"(f) : "v"(fp));
          // legit values during poll-t are {t-1, t, t+1}: accept only f-t<=1
          // (unsigned) so stale flags from a previous launch can never unlock.
          if (!__ballot((f - tgt) > 1u)) break;
          __builtin_amdgcn_s_sleep(1);
        }
        __builtin_amdgcn_fence(__ATOMIC_ACQUIRE, "agent");
        __builtin_amdgcn_sched_barrier(0);
      }

      // h-part: this wave's K-quarter (8 ksteps). A via sc1 from MALL, B VGPRs.
      const __bf16* hbL = hbuf + (p * 2 + rb) * HBUF_SLAB + (w * 8) * 512 + l * 8;
      u32x4 A[8];
      #pragma unroll
      for (int i = 0; i < 8; ++i) A[i] = ldg_dev16(hbL + i * 512);

      CLAIMW4("4", A, 0);
      #pragma unroll
      for (int i = 0; i < 4; ++i)
        #pragma unroll
        for (int ntI = 0; ntI < 4; ++ntI)
          acc[ntI] = __builtin_amdgcn_mfma_f32_16x16x32_bf16(asbf(A[i]), breg[ntI][i], acc[ntI], 0, 0, 0);
      CLAIMW4("0", A, 4);
      #pragma unroll
      for (int i = 4; i < 8; ++i)
        #pragma unroll
        for (int ntI = 0; ntI < 4; ++ntI)
          acc[ntI] = __builtin_amdgcn_mfma_f32_16x16x32_bf16(asbf(A[i]), breg[ntI][i], acc[ntI], 0, 0, 0);
    }

    // WAR guard: gate-phase red_lds reads of step t-1 must finish in ALL waves
    // before this step's deposit overwrites them (the old poll-barrier used to
    // provide this; with per-wave polls it must be explicit).
    __syncthreads();

    // ---- deposit K-partials (conflict-free banking) ----
    #pragma unroll
    for (int g = 0; g < 4; ++g)
      #pragma unroll
      for (int r = 0; r < 4; ++r)
        red_lds[(((w * 4 + g) * 4 + r) * 4 + qh) * 32 + n16 * 2 + (qh & 1)] = acc[g][r];
    __syncthreads();

    // ---- gate phase: own cell (grow, j0+n16); own partial from register ----
    {
      __bf16* hw = hbuf + (p * 2 + wb) * HBUF_SLAB;
      float gv[4];
      #pragma unroll
      for (int g = 0; g < 4; ++g) {
        // own wave's partial for r = w (wave-uniform select)
        float own = (w == 0) ? acc[g][0] : (w == 1) ? acc[g][1]
                  : (w == 2) ? acc[g][2] : acc[g][3];
        float s = own + bias_r[g];
        #pragma unroll
        for (int wo = 0; wo < 4; ++wo)
          if (wo != w)   // w wave-uniform: 3 reads survive per wave
            s += red_lds[(((wo * 4 + g) * 4 + w) * 4 + qh) * 32 + n16 * 2 + (qh & 1)];
        gv[g] = s;
      }
      float i_ = sigmoid_f(gv[0]);
      float f_ = sigmoid_f(gv[1]);
      float g_ = tanh_f(gv[2]);
      float o_ = sigmoid_f(gv[3]);
      float c  = f_ * creg + i_ * g_;
      creg = c;
      float h  = o_ * tanh_f(c);

      // pack 2 adjacent cols via shfl, even lanes store one dword
      union { __bf16 b; unsigned short u; } cv; cv.b = (__bf16)h;
      unsigned int hu = (unsigned int)cv.u;
      unsigned int partner = __shfl_xor(hu, 1);
      if ((n16 & 1) == 0) {
        unsigned int dw = hu | (partner << 16);
        int k = j0 + n16;
        int kk = k >> 5, q2 = (k >> 3) & 3, jj = k & 7;
        stg_dev4(hw + kk * 512 + (q2 * 16 + grow) * 8 + jj, dw);
      }
      if (t == SS - 1) hlast[(p * MG + grow) * HH + j0 + n16] = h;
    }

    // ---- per-wave signal: drain own wave's stores, compiler release fence,
    // then lane0 releases the wave-flag ----
    asm volatile("s_waitcnt vmcnt(0)" ::: "memory");
    __builtin_amdgcn_fence(__ATOMIC_RELEASE, "agent");
    if (t < SS - 1 && l == 0) {
      stg_dev4(gflags + q * 4 + w, (unsigned int)(t + 1));
    }
  }
}

__global__ void fc_kernel(const float* __restrict__ hlast, const float* __restrict__ W_fc,
                          const float* __restrict__ b_fc, float* __restrict__ out) {
  int b = blockIdx.x;            // 128
  int t = threadIdx.x;           // 256
  int o = t >> 2, part = t & 3;
  const float* hr = hlast + b * HH;
  const float* wr = W_fc + o * HH;
  float s = 0.f;
  #pragma unroll 4
  for (int k0 = part * 4; k0 < HH; k0 += 16) {
    float4 hv = *(const float4*)(hr + k0);
    float4 wv = *(const float4*)(wr + k0);
    s += hv.x * wv.x + hv.y * wv.y + hv.z * wv.z + hv.w * wv.w;
  }
  s += __shfl_xor(s, 1);
  s += __shfl_xor(s, 2);
  if (part == 0) out[b * OO + o] = s + b_fc[o];
}

extern "C" void kernel_launch(void* const* d_in, const int* in_sizes, int n_in,
                              void* d_out, int out_size, void* d_ws, size_t ws_size,
                              hipStream_t stream) {
  const float* x    = (const float*)d_in[0];
  const float* mask = (const float*)d_in[1];
  const float* ti   = (const float*)d_in[2];
  const float* W_ih = (const float*)d_in[3];
  const float* W_hh = (const float*)d_in[4];
  const float* b_ih = (const float*)d_in[5];
  const float* b_hh = (const float*)d_in[6];
  const float* W_fc = (const float*)d_in[7];
  const float* b_fc = (const float*)d_in[8];
  float* out = (float*)d_out;

  char* ws = (char*)d_ws;
  unsigned int* flags = (unsigned int*)ws;
  __bf16* hbuf  = (__bf16*)(ws + WS_HBUF);
  float*  hlast = (float*)(ws + WS_HLAST);
  __bf16* xtp   = (__bf16*)(ws + WS_XTP);
  __bf16* wihp  = (__bf16*)(ws + WS_WIHP);

  // zero flags only (8 KB): hbuf is never read before write now (t=0 skips
  // h-part), and the window-poll rejects stale flag values anyway.
  hipMemsetAsync(ws, 0, WS_HBUF, stream);

  prepack_kernel<<<(SS * NGROUP * XTP_TP) / 256, 256, 0, stream>>>(x, mask, ti, xtp);
  wih_prepack<<<(GBLK * WIH_BLK) / 256, 256, 0, stream>>>(W_ih, wihp);
  lstm_scan<<<NGROUP * GBLK, 256, 0, stream>>>(W_hh, b_ih, b_hh, xtp, wihp, hbuf, hlast, flags);
  fc_kernel<<<BB, 256, 0, stream>>>(hlast, W_fc, b_fc, out);
}

// Round 2
// 2093.340 us; speedup vs baseline: 10.3688x; 10.3688x over previous
//
#include <hip/hip_runtime.h>
#include <hip/hip_bf16.h>

typedef __bf16 bf16x8 __attribute__((ext_vector_type(8)));
typedef float f32x4 __attribute__((ext_vector_type(4)));
typedef unsigned int u32x4 __attribute__((ext_vector_type(4)));

#define BB   128
#define SS   512
#define DD   128
#define HH   1024
#define OO   64
#define IIN  257

// 8 batch groups (16 rows) x 64 blocks; block owns 16 h-cols (64 gate cols).
// 4 waves = 4 K-quarters, W_hh B-frags persistent in VGPRs. 2 blocks/CU from
// different groups hide each other's sync-chain latency.
#define NGROUP 8
#define GBLK   64
#define MG     16
#define KK_H   32     // 1024/32 ksteps
#define KK_X   9      // 288/32

#define XTP_TP    (KK_X*512)      // 4608 bf16 per (t,p)
#define HBUF_SLAB (KK_H*512)      // 16384 bf16 = 32 KB per (p,buf)
#define WIH_BLK   (4*KK_X*512)    // 18432 bf16 per q

// ws layout (bytes): flags 8K | hbuf 512K | hlast 512K | xtp 36M | wihp 2.25M
#define WS_HBUF  8192
#define WS_HLAST 532480
#define WS_XTP   1056768
#define WS_WIHP  38805504

// ---- device-scope (sc1) ops: bypass L1/L2, coherent at MALL. NO agent-scope
// compiler fences anywhere: they emit buffer_inv/buffer_wbl2 which invalidate
// the L2-resident xtp/wihp/W_hh working set every timestep (measured: 10x
// regression, FETCH_SIZE 749 MB). Ordering is done purely with vmcnt drains
// on the sc1 stream, which is coherent at MALL by construction.
__device__ __forceinline__ u32x4 ldg_dev16(const void* p) {
  u32x4 r;
  asm volatile("global_load_dwordx4 %0, %1, off sc1" : "=v"(r) : "v"(p));
  return r;
}
__device__ __forceinline__ void stg_dev4(void* p, unsigned int v) {
  asm volatile("global_store_dword %0, %1, off sc1" :: "v"(p), "v"(v));
}
__device__ __forceinline__ bf16x8 asbf(u32x4 v) {
  union { u32x4 u; bf16x8 h; } c; c.u = v; return c.h;
}

#define CLAIMW4(CNTSTR, A, O)                                        \
  asm volatile("s_waitcnt vmcnt(" CNTSTR ")"                         \
    : "+v"((A)[(O)]), "+v"((A)[(O)+1]), "+v"((A)[(O)+2]), "+v"((A)[(O)+3]))

// Zero the flag region with sc1 stores so the zeros land at MALL — the same
// coherence point the scan kernel's sc1 polls read. hipMemsetAsync went via
// the normal L2 path and could alias against prior-launch sc1 flag values
// still live at MALL (the round-0 post-timing flake).
__global__ void flag_init(unsigned int* __restrict__ flags) {
  stg_dev4(flags + blockIdx.x * 256 + threadIdx.x, 0u);
}

// xtp A-frags (16x16x32 A: m=lane&15, k=kk*32+(lane>>4)*8+j):
// idx = ((t*8+p)*9 + kk)*512 + l*8 + j
__global__ void prepack_kernel(const float* __restrict__ x, const float* __restrict__ mask,
                               const float* __restrict__ ti, __bf16* __restrict__ xtp) {
  int idx = blockIdx.x * 256 + threadIdx.x;        // 18,874,368
  int j = idx & 7, l = (idx >> 3) & 63;
  int rest = idx >> 9;
  int kk = rest % 9;
  int rest2 = rest / 9;
  int p = rest2 & 7;
  int t = rest2 >> 3;
  int b = p * MG + (l & 15);
  int k = kk * 32 + ((l >> 4) << 3) + j;
  float v;
  if (k < 128)       v = x[(b * SS + t) * DD + k];
  else if (k < 256)  v = mask[(b * SS + t) * DD + (k - 128)];
  else if (k == 256) v = ti[b * SS + t];
  else               v = 0.f;
  xtp[idx] = (__bf16)v;
}

// W_ih B-frags per col-slice q: [q][nt][kk][lane][8], nt = gate
__global__ void wih_prepack(const float* __restrict__ W_ih, __bf16* __restrict__ wihp) {
  int idx = blockIdx.x * 256 + threadIdx.x;        // 1,179,648
  int j = idx & 7, l = (idx >> 3) & 63;
  int rest = idx >> 9;
  int kk = rest % 9;
  int rest2 = rest / 9;
  int nt = rest2 & 3, q = rest2 >> 2;
  int col = nt * HH + q * 16 + (l & 15);
  int k = kk * 32 + ((l >> 4) << 3) + j;
  wihp[idx] = (k < IIN) ? (__bf16)W_ih[col * IIN + k] : (__bf16)0.f;
}

__device__ __forceinline__ float sigmoid_f(float v) { return 1.f / (1.f + __expf(-v)); }
__device__ __forceinline__ float tanh_f(float v)    { return 1.f - 2.f / (__expf(2.f * v) + 1.f); }

__launch_bounds__(256, 2)
__global__ void lstm_scan(const float* __restrict__ W_hh,
                          const float* __restrict__ b_ih, const float* __restrict__ b_hh,
                          const __bf16* __restrict__ xtp, const __bf16* __restrict__ wihp,
                          __bf16* __restrict__ hbuf,
                          float* __restrict__ hlast, unsigned int* __restrict__ flags) {
  // conflict-free reduce buffer: slot(w,g,r,qh,n16) =
  //   (((w*4+g)*4+r)*4+qh)*32 + n16*2 + (qh&1)   -> bank = 2*n16+(qh&1), 2-way
  __shared__ float red_lds[8192];   // 32 KB

  const int tid = threadIdx.x;
  const int bid = blockIdx.x;
  const int p = bid >> 6;                      // batch group [0,8)
  const int q = bid & 63;                      // col slice within group
  const int j0 = q * 16;                       // owned h-cols [j0, j0+16)

  const int w = tid >> 6, l = tid & 63;        // wave = K-quarter
  const int n16 = l & 15, qh = l >> 4;
  unsigned int* gflags = flags + p * 256;      // 64 blocks x 4 wave-flags

  // ---- W_hh B-fragments persistent in VGPRs: [nt][i], kk = w*8+i ----
  bf16x8 breg[4][8];
  #pragma unroll
  for (int ntI = 0; ntI < 4; ++ntI) {
    const float* wrow = W_hh + (size_t)(ntI * HH + j0 + n16) * HH;
    #pragma unroll
    for (int i = 0; i < 8; ++i) {
      const float* src = wrow + (w * 8 + i) * 32 + qh * 8;
      bf16x8 bv;
      #pragma unroll
      for (int jj = 0; jj < 8; ++jj) bv[jj] = (__bf16)src[jj];
      breg[ntI][i] = bv;
    }
  }

  // gate-phase cell ownership: this thread owns (row = qh*4 + w, col = j0+n16)
  const int grow = qh * 4 + w;
  float bias_r[4];
  #pragma unroll
  for (int g = 0; g < 4; ++g)
    bias_r[g] = b_ih[g * HH + j0 + n16] + b_hh[g * HH + j0 + n16];
  float creg = 0.f;

  // x-part K split over waves: kk in [xs, xe)
  const int xs = (w == 0) ? 0 : (2 * w + 1);
  const int xe = xs + ((w == 0) ? 3 : 2);

  for (int t = 0; t < SS; ++t) {
    const int rb = t & 1, wb = rb ^ 1;
    f32x4 acc[4];
    #pragma unroll
    for (int ntI = 0; ntI < 4; ++ntI) acc[ntI] = (f32x4){0.f, 0.f, 0.f, 0.f};

    // x-part (this wave's K-slice), pre-poll; A from xtp, B from wihp (cached)
    for (int kk = xs; kk < xe; ++kk) {
      const __bf16* xb = xtp + ((size_t)(t * 8 + p) * KK_X + kk) * 512 + l * 8;
      bf16x8 a = *(const bf16x8*)xb;
      #pragma unroll
      for (int ntI = 0; ntI < 4; ++ntI) {
        bf16x8 b = *(const bf16x8*)(wihp + ((size_t)(q * 4 + ntI) * KK_X + kk) * 512 + l * 8);
        acc[ntI] = __builtin_amdgcn_mfma_f32_16x16x32_bf16(a, b, acc[ntI], 0, 0, 0);
      }
    }

    // ---- per-wave poll + h-part. Wave w consumes h-cols [256w, 256w+256) ==
    // blocks q' in [16w, 16w+16) == flags gflags[64w + lane] (1 dword/lane).
    // Union of the block's 4 wave-polls covers all 256 flags before the
    // deposit barrier, so the slab WAR-safety argument is unchanged.
    // t==0: h0 == 0 -> skip h-part entirely; hbuf is never read before being
    // written under flag protection.
    if (t > 0) {
      {
        const unsigned int tgt = (unsigned int)t;
        const unsigned int* fp = gflags + (w << 6) + l;
        for (;;) {
          unsigned int f;
          asm volatile("global_load_dword %0, %1, off sc1\n\t"
                       "s_waitcnt vmcnt(0)"
                       : "=v"(f) : "v"(fp));
          // legit values during poll-t are {t-1, t, t+1}: accept only f-t<=1
          // (unsigned) so stale flags from a previous launch can never unlock.
          if (!__ballot((f - tgt) > 1u)) break;
          __builtin_amdgcn_s_sleep(1);
        }
        __builtin_amdgcn_sched_barrier(0);
      }

      // h-part: this wave's K-quarter (8 ksteps). A via sc1 from MALL, B VGPRs.
      const __bf16* hbL = hbuf + (p * 2 + rb) * HBUF_SLAB + (w * 8) * 512 + l * 8;
      u32x4 A[8];
      #pragma unroll
      for (int i = 0; i < 8; ++i) A[i] = ldg_dev16(hbL + i * 512);

      CLAIMW4("4", A, 0);
      #pragma unroll
      for (int i = 0; i < 4; ++i)
        #pragma unroll
        for (int ntI = 0; ntI < 4; ++ntI)
          acc[ntI] = __builtin_amdgcn_mfma_f32_16x16x32_bf16(asbf(A[i]), breg[ntI][i], acc[ntI], 0, 0, 0);
      CLAIMW4("0", A, 4);
      #pragma unroll
      for (int i = 4; i < 8; ++i)
        #pragma unroll
        for (int ntI = 0; ntI < 4; ++ntI)
          acc[ntI] = __builtin_amdgcn_mfma_f32_16x16x32_bf16(asbf(A[i]), breg[ntI][i], acc[ntI], 0, 0, 0);
    }

    // WAR guard: gate-phase red_lds reads of step t-1 must finish in ALL waves
    // before this step's deposit overwrites them.
    __syncthreads();

    // ---- deposit K-partials (conflict-free banking) ----
    #pragma unroll
    for (int g = 0; g < 4; ++g)
      #pragma unroll
      for (int r = 0; r < 4; ++r)
        red_lds[(((w * 4 + g) * 4 + r) * 4 + qh) * 32 + n16 * 2 + (qh & 1)] = acc[g][r];
    __syncthreads();

    // ---- gate phase: own cell (grow, j0+n16); own partial from register ----
    {
      __bf16* hw = hbuf + (p * 2 + wb) * HBUF_SLAB;
      float gv[4];
      #pragma unroll
      for (int g = 0; g < 4; ++g) {
        // own wave's partial for r = w (wave-uniform select)
        float own = (w == 0) ? acc[g][0] : (w == 1) ? acc[g][1]
                  : (w == 2) ? acc[g][2] : acc[g][3];
        float s = own + bias_r[g];
        #pragma unroll
        for (int wo = 0; wo < 4; ++wo)
          if (wo != w)   // w wave-uniform: 3 reads survive per wave
            s += red_lds[(((wo * 4 + g) * 4 + w) * 4 + qh) * 32 + n16 * 2 + (qh & 1)];
        gv[g] = s;
      }
      float i_ = sigmoid_f(gv[0]);
      float f_ = sigmoid_f(gv[1]);
      float g_ = tanh_f(gv[2]);
      float o_ = sigmoid_f(gv[3]);
      float c  = f_ * creg + i_ * g_;
      creg = c;
      float h  = o_ * tanh_f(c);

      // pack 2 adjacent cols via shfl, even lanes store one dword
      union { __bf16 b; unsigned short u; } cv; cv.b = (__bf16)h;
      unsigned int hu = (unsigned int)cv.u;
      unsigned int partner = __shfl_xor(hu, 1);
      if ((n16 & 1) == 0) {
        unsigned int dw = hu | (partner << 16);
        int k = j0 + n16;
        int kk = k >> 5, q2 = (k >> 3) & 3, jj = k & 7;
        stg_dev4(hw + kk * 512 + (q2 * 16 + grow) * 8 + jj, dw);
      }
      if (t == SS - 1) hlast[(p * MG + grow) * HH + j0 + n16] = h;
    }

    // ---- per-wave signal: drain own wave's sc1 stores (release ordering on
    // the MALL-coherent stream), then lane0 releases the wave-flag ----
    asm volatile("s_waitcnt vmcnt(0)" ::: "memory");
    if (t < SS - 1 && l == 0) {
      stg_dev4(gflags + q * 4 + w, (unsigned int)(t + 1));
    }
  }
}

__global__ void fc_kernel(const float* __restrict__ hlast, const float* __restrict__ W_fc,
                          const float* __restrict__ b_fc, float* __restrict__ out) {
  int b = blockIdx.x;            // 128
  int t = threadIdx.x;           // 256
  int o = t >> 2, part = t & 3;
  const float* hr = hlast + b * HH;
  const float* wr = W_fc + o * HH;
  float s = 0.f;
  #pragma unroll 4
  for (int k0 = part * 4; k0 < HH; k0 += 16) {
    float4 hv = *(const float4*)(hr + k0);
    float4 wv = *(const float4*)(wr + k0);
    s += hv.x * wv.x + hv.y * wv.y + hv.z * wv.z + hv.w * wv.w;
  }
  s += __shfl_xor(s, 1);
  s += __shfl_xor(s, 2);
  if (part == 0) out[b * OO + o] = s + b_fc[o];
}

extern "C" void kernel_launch(void* const* d_in, const int* in_sizes, int n_in,
                              void* d_out, int out_size, void* d_ws, size_t ws_size,
                              hipStream_t stream) {
  const float* x    = (const float*)d_in[0];
  const float* mask = (const float*)d_in[1];
  const float* ti   = (const float*)d_in[2];
  const float* W_ih = (const float*)d_in[3];
  const float* W_hh = (const float*)d_in[4];
  const float* b_ih = (const float*)d_in[5];
  const float* b_hh = (const float*)d_in[6];
  const float* W_fc = (const float*)d_in[7];
  const float* b_fc = (const float*)d_in[8];
  float* out = (float*)d_out;

  char* ws = (char*)d_ws;
  unsigned int* flags = (unsigned int*)ws;
  __bf16* hbuf  = (__bf16*)(ws + WS_HBUF);
  float*  hlast = (float*)(ws + WS_HLAST);
  __bf16* xtp   = (__bf16*)(ws + WS_XTP);
  __bf16* wihp  = (__bf16*)(ws + WS_WIHP);

  // zero flags with sc1 stores (MALL-coherent with the scan kernel's polls);
  // hbuf needs no init: t=0 skips the h-part, so it is never read before a
  // flag-protected write.
  flag_init<<<8, 256, 0, stream>>>(flags);

  prepack_kernel<<<(SS * NGROUP * XTP_TP) / 256, 256, 0, stream>>>(x, mask, ti, xtp);
  wih_prepack<<<(GBLK * WIH_BLK) / 256, 256, 0, stream>>>(W_ih, wihp);
  lstm_scan<<<NGROUP * GBLK, 256, 0, stream>>>(W_hh, b_ih, b_hh, xtp, wihp, hbuf, hlast, flags);
  fc_kernel<<<BB, 256, 0, stream>>>(hlast, W_fc, b_fc, out);
}